// Round 1
// baseline (341.845 us; speedup 1.0000x reference)
//
#include <hip/hip_runtime.h>
#include <math.h>

#define CRF_B 256
#define CRF_S 2048
#define CRF_K 64
#define NSEG 128
#define SEGL 16
#define BURN 16
#define DEPTH 32  // BURN + 16 accumulation steps

typedef short bf16x8 __attribute__((ext_vector_type(8)));  // 8 bf16 = 4 VGPRs
typedef float f32x4 __attribute__((ext_vector_type(4)));

// Compiler-only fence; per-wave DS ops are processed in-order by the LDS pipe
// (write->read visibility verified rounds 1-4, absmax 0). Waves touch disjoint
// LDS regions during the scan, so no __syncthreads until the fused epilogue.
__device__ __forceinline__ void lds_fence() { asm volatile("" ::: "memory"); }

__device__ __forceinline__ unsigned bf16rne(float x) {
    unsigned u = __float_as_uint(x);
    return (u + 0x7FFFu + ((u >> 16) & 1u)) >> 16;
}
// trunc-bf16 pack of (x,y) via one v_perm_b32 (validated round 4, absmax 0).
__device__ __forceinline__ unsigned pktrunc(float x, float y) {
    return __builtin_amdgcn_perm(__float_as_uint(y), __float_as_uint(x), 0x07060302u);
}
__device__ __forceinline__ int expOf(float m) {  // e such that m*2^-e in [0.5,1)
    return ((__float_as_int(m) >> 23) & 255) - 126;
}

// Block = batch b, 8 waves (512 thr); wave w owns chains s = 16w+c (c=lane&15).
// Chain s: steps k=0..31 apply matrix step t = s*16-16+k (clamped to >=0);
// k<16 burn-in re-derives the direction from uniform, k>=16 accumulates
// t in [s*16, s*16+15]. Chain 0 gets exact alpha_0 injected at k=16 (its
// computed t=0 "step" is discarded). Max t = 127*16+15 = 2047.
// MFMA (verified r3/r4): D[state][chain] = sum_i E[i][state]*P[chain][i];
// A[m=lane&15][k=q*8+j] static E-frags, B = P via LDS, C col=lane&15 (chain),
// row(state-in-group) = q*4+reg.
//
// Emission loads (this round): each global_load_dwordx4 now reads 4 contiguous
// 256 B row-chunks (chains 4i+h, h=lane>>4; unit m=lane&15) instead of 16
// scattered 64 B segments. Data is redistributed to consumer lanes (c,q) via a
// per-wave LDS staging buffer each step (same-wave in-order write->read, like
// the P exchange). The f32 values reaching expf are bit-identical to before.
__global__ __launch_bounds__(512, 2) void crf_scan(
    const float* __restrict__ scores, const int* __restrict__ states,
    const float* __restrict__ trans, const float* __restrict__ source,
    const float* __restrict__ sink, float* __restrict__ lossOut)
{
    const int tid = threadIdx.x;
    const int lane = tid & 63;
    const int w = tid >> 6;   // wave 0..7
    const int b = blockIdx.x;
    const int c = lane & 15;  // chain-within-wave
    const int q = lane >> 4;  // quad
    const int s = w * 16 + c; // global segment id 0..127

    __shared__ __align__(16) short Pbuf[8][16 * 72];  // per-wave [chain][state], stride 72
    __shared__ __align__(16) float Ebuf[8][16 * 68];  // per-wave emission stage, stride 68 f32 (272 B)
    __shared__ float sC[NSEG];
    __shared__ float gW[8];
    __shared__ float dotSh;
    short* myP = Pbuf[w];
    float* myE = Ebuf[w];

    const float* scb = scores + (size_t)b * CRF_S * CRF_K;

    // ---------- gold-path partial (this wave's 1/8 of the sequence) ----------
    {
        const int* st = states + b * CRF_S;
        float g = 0.f;
#pragma unroll
        for (int it = 0; it < 4; ++it) {
            int p = w * 256 + it * 64 + lane;
            int cur = st[p];
            g += scb[(size_t)p * CRF_K + cur];
            if (p > 0) g += trans[st[p - 1] * CRF_K + cur];
            if (p == 0) g += source[cur];
            if (p == CRF_S - 1) g += sink[cur];
        }
#pragma unroll
        for (int m = 32; m >= 1; m >>= 1) g += __shfl_xor(g, m, 64);
        if (lane == 0) gW[w] = g;
    }

    // ---------- static E fragments (A operand), bf16 RNE ----------
    bf16x8 Af[4][2];
#pragma unroll
    for (int g4 = 0; g4 < 4; ++g4)
#pragma unroll
        for (int h = 0; h < 2; ++h) {
            bf16x8 t;
#pragma unroll
            for (int jv = 0; jv < 8; ++jv)
                t[jv] = (short)bf16rne(__expf(trans[(h * 32 + q * 8 + jv) * CRF_K + g4 * 16 + c]));
            Af[g4][h] = t;
        }

    // exact init for chain 0: exp(source + scores[b][0][:]) (layout depends on q only)
    float ini[16];
#pragma unroll
    for (int i = 0; i < 16; ++i) {
        int st8 = 16 * (i >> 2) + 4 * q + (i & 3);
        ini[i] = __expf(source[st8] + scb[st8]);
    }

    // P init: ones (bf16 1.0 = 0x3F80)
#pragma unroll
    for (int g4 = 0; g4 < 4; ++g4)
        *(int2*)(myP + c * 72 + 16 * g4 + 4 * q) =
            make_int2((int)0x3F803F80u, (int)0x3F803F80u);
    lds_fence();
    bf16x8 bf0 = *(const bf16x8*)(myP + c * 72 + q * 8);
    bf16x8 bf1 = *(const bf16x8*)(myP + c * 72 + 32 + q * 8);

    // emission prefetch pipeline (distance 4): instruction i reads chains
    // 4i+h_ (h_=lane>>4), contiguous 16 B unit m_=lane&15 of row t. Each
    // instruction = 4 x 256 B contiguous chunks (4 KB apart) vs old 16 x 64 B.
    const int m_ = lane & 15;
    const int h_ = lane >> 4;
    float4 raw4[4][4];  // [slot][chunk-instr]
    int srow[4];
#pragma unroll
    for (int i = 0; i < 4; ++i) srow[i] = (w * 16 + 4 * i + h_) * SEGL - BURN;
    auto ld4 = [&](int k) {
        const int sl = k & 3;
#pragma unroll
        for (int i = 0; i < 4; ++i) {
            int t = min(max(srow[i] + k, 0), CRF_S - 1);
            raw4[sl][i] = *(const float4*)(scb + (size_t)t * CRF_K + m_ * 4);
        }
    };
#pragma unroll
    for (int k = 0; k < 4; ++k) ld4(k);

    float v[16];
    int cint = 0, e_pend = 0;

    for (int kk = 0; kk < DEPTH; kk += 4) {
#pragma unroll
        for (int ph = 0; ph < 4; ++ph) {
            const int k = kk + ph;
            // (1) stage this step's rows to LDS, read back own (c,q) slices.
            // write: chain 4i+h_, unit m_ -> addr (4i+h_)*68 + m_*4 (16B granule)
            // read:  chain c, units u=4*g4+q  (identical f32 values as before)
#pragma unroll
            for (int i = 0; i < 4; ++i)
                *(float4*)(myE + (4 * i + h_) * 68 + m_ * 4) = raw4[ph][i];
            lds_fence();
            float4 sl4[4];
#pragma unroll
            for (int g4 = 0; g4 < 4; ++g4)
                sl4[g4] = *(const float4*)(myE + c * 68 + (4 * g4 + q) * 4);
            float es[16];
#pragma unroll
            for (int g4 = 0; g4 < 4; ++g4) {
                es[g4 * 4 + 0] = __expf(sl4[g4].x);
                es[g4 * 4 + 1] = __expf(sl4[g4].y);
                es[g4 * 4 + 2] = __expf(sl4[g4].z);
                es[g4 * 4 + 3] = __expf(sl4[g4].w);
            }
            // (2) MFMA: D[state][chain]
            f32x4 acc[4];
#pragma unroll
            for (int g4 = 0; g4 < 4; ++g4) {
                f32x4 z = {0.f, 0.f, 0.f, 0.f};
                z = __builtin_amdgcn_mfma_f32_16x16x32_bf16(Af[g4][0], bf0, z, 0, 0, 0);
                z = __builtin_amdgcn_mfma_f32_16x16x32_bf16(Af[g4][1], bf1, z, 0, 0, 0);
                acc[g4] = z;
            }
            // (3) v = acc*es, applying the pending strip on period boundaries
            if (ph == 0) {
                const float s2 = ldexpf(1.0f, -e_pend);
                cint += e_pend;
#pragma unroll
                for (int i = 0; i < 16; ++i) v[i] = acc[i >> 2][i & 3] * es[i] * s2;
            } else {
#pragma unroll
                for (int i = 0; i < 16; ++i) v[i] = acc[i >> 2][i & 3] * es[i];
            }
            // (4a) end-of-burn canonical strip (all chains), reset bookkeeping
            if (k == BURN - 1) {
                float mc = v[0];
#pragma unroll
                for (int i = 1; i < 16; ++i) mc = fmaxf(mc, v[i]);
                mc = fmaxf(mc, __shfl_xor(mc, 16, 64));
                mc = fmaxf(mc, __shfl_xor(mc, 32, 64));
                const float sc2 = ldexpf(1.0f, -expOf(mc));
#pragma unroll
                for (int i = 0; i < 16; ++i) v[i] *= sc2;
                cint = 0;
                e_pend = 0;
            }
            // (4b) chain-0 exact injection (its t=0 "step" result is discarded)
            if (k == BURN) {
                if (s == 0) {
#pragma unroll
                    for (int i = 0; i < 16; ++i) v[i] = ini[i];
                }
                float mc = v[0];
#pragma unroll
                for (int i = 1; i < 16; ++i) mc = fmaxf(mc, v[i]);
                mc = fmaxf(mc, __shfl_xor(mc, 16, 64));
                mc = fmaxf(mc, __shfl_xor(mc, 32, 64));
                const int ec = expOf(mc);
                if (s == 0) {
                    const float sc2 = ldexpf(1.0f, -ec);
#pragma unroll
                    for (int i = 0; i < 16; ++i) v[i] *= sc2;
                    cint = ec;
                }
            }
            // (5) periodic strip compute (stale-by-1-step; applied at next ph==0)
            if (ph == 3 && k != BURN - 1) {
                float mx = v[0];
#pragma unroll
                for (int i = 1; i < 16; ++i) mx = fmaxf(mx, v[i]);
                mx = fmaxf(mx, __shfl_xor(mx, 16, 64));
                mx = fmaxf(mx, __shfl_xor(mx, 32, 64));
                e_pend = expOf(mx);
            }
            // (6) pack (trunc) + write own chain's 16 states; read next B frags
#pragma unroll
            for (int g4 = 0; g4 < 4; ++g4) {
                unsigned lo = pktrunc(v[g4 * 4 + 0], v[g4 * 4 + 1]);
                unsigned hi = pktrunc(v[g4 * 4 + 2], v[g4 * 4 + 3]);
                *(int2*)(myP + c * 72 + 16 * g4 + 4 * q) = make_int2((int)lo, (int)hi);
            }
            lds_fence();
            bf0 = *(const bf16x8*)(myP + c * 72 + q * 8);
            bf1 = *(const bf16x8*)(myP + c * 72 + 32 + q * 8);
            // (7) prefetch emissions for step k+4 (clamped; harmless overrun)
            ld4(k + 4);
        }
    }

    // final canonical strip (telescopes with next segment's burn-in canonical)
    float mf = v[0];
#pragma unroll
    for (int i = 1; i < 16; ++i) mf = fmaxf(mf, v[i]);
    mf = fmaxf(mf, __shfl_xor(mf, 16, 64));
    mf = fmaxf(mf, __shfl_xor(mf, 32, 64));
    const int ef = expOf(mf);
    cint += ef;
    const float sf = ldexpf(1.0f, -ef);

    // ---------- fused per-batch epilogue ----------
    if (q == 0) sC[s] = (float)cint * 0.6931471805599453f;
    if (w == 7) {
        // chain 127 lanes: dot(vlast, exp(sink))
        float pd = 0.f;
        if (c == 15) {
#pragma unroll
            for (int i = 0; i < 16; ++i) {
                int st8 = 16 * (i >> 2) + 4 * q + (i & 3);
                pd += v[i] * sf * __expf(sink[st8]);
            }
        }
        pd += __shfl_xor(pd, 16, 64);
        pd += __shfl_xor(pd, 32, 64);
        if (lane == 15) dotSh = pd;
    }
    __syncthreads();
    if (w == 0) {
        float t2 = sC[lane] + sC[lane + 64];
#pragma unroll
        for (int m = 32; m >= 1; m >>= 1) t2 += __shfl_xor(t2, m, 64);
        if (lane == 0) {
            float gold = 0.f;
#pragma unroll
            for (int i = 0; i < 8; ++i) gold += gW[i];
            lossOut[b] = t2 + logf(dotSh) - gold;
        }
    }
}

__global__ __launch_bounds__(256) void crf_finish(
    const float* __restrict__ loss, float* __restrict__ out)
{
    const int b = threadIdx.x;
    __shared__ float red[256];
    red[b] = loss[b];
    __syncthreads();
    for (int s2 = 128; s2 > 0; s2 >>= 1) {
        if (b < s2) red[b] += red[b + s2];
        __syncthreads();
    }
    if (b == 0) out[0] = red[0] * (1.0f / CRF_B);
}

extern "C" void kernel_launch(void* const* d_in, const int* in_sizes, int n_in,
                              void* d_out, int out_size, void* d_ws, size_t ws_size,
                              hipStream_t stream) {
    const float* scores = (const float*)d_in[0];
    const int*   states = (const int*)d_in[1];
    const float* trans  = (const float*)d_in[2];
    const float* source = (const float*)d_in[3];
    const float* sink   = (const float*)d_in[4];

    float* loss = (float*)d_ws;
    float* out = (float*)d_out;

    crf_scan<<<CRF_B, 512, 0, stream>>>(scores, states, trans, source, sink, loss);
    crf_finish<<<1, 256, 0, stream>>>(loss, out);
}

// Round 2
// 223.300 us; speedup vs baseline: 1.5309x; 1.5309x over previous
//
#include <hip/hip_runtime.h>
#include <math.h>

#define CRF_B 256
#define CRF_S 2048
#define CRF_K 64
#define NSEG 128
#define SEGL 16
#define BURN 16
#define DEPTH 32  // BURN + 16 accumulation steps

typedef short bf16x8 __attribute__((ext_vector_type(8)));  // 8 bf16 = 4 VGPRs
typedef float f32x4 __attribute__((ext_vector_type(4)));
typedef __attribute__((address_space(3))) void lds_void;
typedef const __attribute__((address_space(1))) void glb_void;

// Compiler-only fence; per-wave DS ops are processed in-order by the LDS pipe
// (write->read visibility verified rounds 1-4 of prior session, absmax 0).
__device__ __forceinline__ void lds_fence() { asm volatile("" ::: "memory"); }

__device__ __forceinline__ unsigned bf16rne(float x) {
    unsigned u = __float_as_uint(x);
    return (u + 0x7FFFu + ((u >> 16) & 1u)) >> 16;
}
// trunc-bf16 pack of (x,y) via one v_perm_b32 (validated earlier, absmax 0).
__device__ __forceinline__ unsigned pktrunc(float x, float y) {
    return __builtin_amdgcn_perm(__float_as_uint(y), __float_as_uint(x), 0x07060302u);
}
__device__ __forceinline__ int expOf(float m) {  // e such that m*2^-e in [0.5,1)
    return ((__float_as_int(m) >> 23) & 255) - 126;
}

// Block = (batch b, half) : 4 waves (256 thr); wave w owns chains sg =
// half*64 + w*16 + c (c = lane&15). Chain sg: steps k=0..31 apply matrix step
// t = sg*16-16+k (clamped >= 0); k<16 burn-in, k>=16 accumulate. Chain 0 gets
// exact alpha_0 injected at k=16. MFMA mapping unchanged from prior session.
//
// Emission path (this round): global_load_lds dwordx4 DMA into a per-wave
// 2-slot LDS double buffer (4 KB/slot = 16 chains x 256 B, LINEAR dest as the
// DMA requires). Each DMA instruction covers 4 contiguous 256 B row-chunks.
// The global source COLUMN is pre-swizzled (unit ^= chain&15) so that the
// swizzled read-back (unit = (4g4+q)^c) is bank-uniform; values reaching expf
// are bit-identical to the round-0 kernel. vmcnt is hand-counted: exactly 4
// DMAs issued per step, wait vmcnt(4) at step start (never drain to 0).
__global__ __launch_bounds__(256, 2) void crf_scan(
    const float* __restrict__ scores, const int* __restrict__ states,
    const float* __restrict__ trans, const float* __restrict__ source,
    const float* __restrict__ sink, float* __restrict__ partOut)
{
    const int tid = threadIdx.x;
    const int lane = tid & 63;
    const int w = tid >> 6;        // wave 0..3
    const int bid = blockIdx.x;
    const int b = bid >> 1;
    const int half = bid & 1;
    const int c = lane & 15;       // chain-within-wave
    const int q = lane >> 4;       // quad
    const int sg = half * 64 + w * 16 + c;  // global segment id 0..127

    __shared__ __align__(16) short Pbuf[4][16 * 72];   // per-wave [chain][state], stride 72
    __shared__ __align__(16) float Ebuf[4][2 * 1024];  // per-wave 2-slot DMA buffer (2 x 4 KB)
    __shared__ float sC[64];
    __shared__ float gW[4];
    __shared__ float dotSh;
    short* myP = Pbuf[w];
    float* myE = Ebuf[w];

    const float* scb = scores + (size_t)b * CRF_S * CRF_K;

    // ---------- gold-path partial (this block's 1/2, this wave's 1/4 of it) ----------
    {
        const int* st = states + b * CRF_S;
        float g = 0.f;
#pragma unroll
        for (int it = 0; it < 4; ++it) {
            int p = half * 1024 + w * 256 + it * 64 + lane;
            int cur = st[p];
            g += scb[(size_t)p * CRF_K + cur];
            if (p > 0) g += trans[st[p - 1] * CRF_K + cur];
            if (p == 0) g += source[cur];
            if (p == CRF_S - 1) g += sink[cur];
        }
#pragma unroll
        for (int m = 32; m >= 1; m >>= 1) g += __shfl_xor(g, m, 64);
        if (lane == 0) gW[w] = g;
    }

    // ---------- static E fragments (A operand), bf16 RNE ----------
    bf16x8 Af[4][2];
#pragma unroll
    for (int g4 = 0; g4 < 4; ++g4)
#pragma unroll
        for (int h = 0; h < 2; ++h) {
            bf16x8 t;
#pragma unroll
            for (int jv = 0; jv < 8; ++jv)
                t[jv] = (short)bf16rne(__expf(trans[(h * 32 + q * 8 + jv) * CRF_K + g4 * 16 + c]));
            Af[g4][h] = t;
        }

    // exact init for chain 0: exp(source + scores[b][0][:]) (layout depends on q only)
    float ini[16];
#pragma unroll
    for (int i = 0; i < 16; ++i) {
        int st8 = 16 * (i >> 2) + 4 * q + (i & 3);
        ini[i] = __expf(source[st8] + scb[st8]);
    }

    // P init: ones (bf16 1.0 = 0x3F80)
#pragma unroll
    for (int g4 = 0; g4 < 4; ++g4)
        *(int2*)(myP + c * 72 + 16 * g4 + 4 * q) =
            make_int2((int)0x3F803F80u, (int)0x3F803F80u);
    lds_fence();
    bf16x8 bf0 = *(const bf16x8*)(myP + c * 72 + q * 8);
    bf16x8 bf1 = *(const bf16x8*)(myP + c * 72 + 32 + q * 8);

    // ---------- emission DMA pipeline (distance 1, 2 slots) ----------
    // Instruction i (i=0..3): 16-lane group h_ covers chain ch=4i+h_; lane's
    // 16 B unit within the 256 B row chunk is m_ ^ ch (pre-swizzled source).
    // LDS dest per instruction: linear 1024 B at slot + i*1024.
    const int m_ = lane & 15;
    const int h_ = lane >> 4;
    int baseT[4], ug[4];
#pragma unroll
    for (int i = 0; i < 4; ++i) {
        int ch = 4 * i + h_;
        baseT[i] = (half * 64 + w * 16 + ch) * SEGL - BURN;
        ug[i] = (m_ ^ ch) & 15;
    }
    auto issue = [&](int k, int sl) {
#pragma unroll
        for (int i = 0; i < 4; ++i) {
            int t = min(max(baseT[i] + k, 0), CRF_S - 1);
            const float* g = scb + (size_t)t * CRF_K + ug[i] * 4;
            float* l = myE + sl * 1024 + i * 256;
            __builtin_amdgcn_global_load_lds((glb_void*)g, (lds_void*)l, 16, 0, 0);
        }
    };
    issue(0, 0);
    issue(1, 1);

    float v[16];
    int cint = 0, e_pend = 0;

    for (int kk = 0; kk < DEPTH; kk += 4) {
#pragma unroll
        for (int ph = 0; ph < 4; ++ph) {
            const int k = kk + ph;
            // (1) wait step-k DMAs (4 newer stay in flight), read es slices,
            // then refill this slot for step k+2 (after lgkmcnt(0) closes the
            // WAR window on the slot).
            asm volatile("s_waitcnt vmcnt(4)" ::: "memory");
            const float* eb = myE + (k & 1) * 1024 + c * 64;
            float4 sl4[4];
#pragma unroll
            for (int g4 = 0; g4 < 4; ++g4)
                sl4[g4] = *(const float4*)(eb + (((4 * g4 + q) ^ c) * 4));
            asm volatile("s_waitcnt lgkmcnt(0)" ::: "memory");
            issue(k + 2, k & 1);  // clamped rows; overrun slots never read
            float es[16];
#pragma unroll
            for (int g4 = 0; g4 < 4; ++g4) {
                es[g4 * 4 + 0] = __expf(sl4[g4].x);
                es[g4 * 4 + 1] = __expf(sl4[g4].y);
                es[g4 * 4 + 2] = __expf(sl4[g4].z);
                es[g4 * 4 + 3] = __expf(sl4[g4].w);
            }
            // (2) MFMA: D[state][chain]
            f32x4 acc[4];
#pragma unroll
            for (int g4 = 0; g4 < 4; ++g4) {
                f32x4 z = {0.f, 0.f, 0.f, 0.f};
                z = __builtin_amdgcn_mfma_f32_16x16x32_bf16(Af[g4][0], bf0, z, 0, 0, 0);
                z = __builtin_amdgcn_mfma_f32_16x16x32_bf16(Af[g4][1], bf1, z, 0, 0, 0);
                acc[g4] = z;
            }
            // (3) v = acc*es, applying the pending strip on period boundaries
            if (ph == 0) {
                const float s2 = ldexpf(1.0f, -e_pend);
                cint += e_pend;
#pragma unroll
                for (int i = 0; i < 16; ++i) v[i] = acc[i >> 2][i & 3] * es[i] * s2;
            } else {
#pragma unroll
                for (int i = 0; i < 16; ++i) v[i] = acc[i >> 2][i & 3] * es[i];
            }
            // (4a) end-of-burn canonical strip (all chains), reset bookkeeping
            if (k == BURN - 1) {
                float mc = v[0];
#pragma unroll
                for (int i = 1; i < 16; ++i) mc = fmaxf(mc, v[i]);
                mc = fmaxf(mc, __shfl_xor(mc, 16, 64));
                mc = fmaxf(mc, __shfl_xor(mc, 32, 64));
                const float sc2 = ldexpf(1.0f, -expOf(mc));
#pragma unroll
                for (int i = 0; i < 16; ++i) v[i] *= sc2;
                cint = 0;
                e_pend = 0;
            }
            // (4b) chain-0 exact injection (its t=0 "step" result is discarded)
            if (k == BURN) {
                if (sg == 0) {
#pragma unroll
                    for (int i = 0; i < 16; ++i) v[i] = ini[i];
                }
                float mc = v[0];
#pragma unroll
                for (int i = 1; i < 16; ++i) mc = fmaxf(mc, v[i]);
                mc = fmaxf(mc, __shfl_xor(mc, 16, 64));
                mc = fmaxf(mc, __shfl_xor(mc, 32, 64));
                const int ec = expOf(mc);
                if (sg == 0) {
                    const float sc2 = ldexpf(1.0f, -ec);
#pragma unroll
                    for (int i = 0; i < 16; ++i) v[i] *= sc2;
                    cint = ec;
                }
            }
            // (5) periodic strip compute (stale-by-1-step; applied at next ph==0)
            if (ph == 3 && k != BURN - 1) {
                float mx = v[0];
#pragma unroll
                for (int i = 1; i < 16; ++i) mx = fmaxf(mx, v[i]);
                mx = fmaxf(mx, __shfl_xor(mx, 16, 64));
                mx = fmaxf(mx, __shfl_xor(mx, 32, 64));
                e_pend = expOf(mx);
            }
            // (6) pack (trunc) + write own chain's 16 states; read next B frags
#pragma unroll
            for (int g4 = 0; g4 < 4; ++g4) {
                unsigned lo = pktrunc(v[g4 * 4 + 0], v[g4 * 4 + 1]);
                unsigned hi = pktrunc(v[g4 * 4 + 2], v[g4 * 4 + 3]);
                *(int2*)(myP + c * 72 + 16 * g4 + 4 * q) = make_int2((int)lo, (int)hi);
            }
            lds_fence();
            bf0 = *(const bf16x8*)(myP + c * 72 + q * 8);
            bf1 = *(const bf16x8*)(myP + c * 72 + 32 + q * 8);
        }
    }

    // final canonical strip (telescopes with next segment's burn-in canonical)
    float mf = v[0];
#pragma unroll
    for (int i = 1; i < 16; ++i) mf = fmaxf(mf, v[i]);
    mf = fmaxf(mf, __shfl_xor(mf, 16, 64));
    mf = fmaxf(mf, __shfl_xor(mf, 32, 64));
    const int ef = expOf(mf);
    cint += ef;
    const float sf = ldexpf(1.0f, -ef);

    // ---------- per-(batch,half) epilogue ----------
    if (q == 0) sC[w * 16 + c] = (float)cint * 0.6931471805599453f;
    if (half == 1 && w == 3) {
        // chain 127 lanes: dot(vlast, exp(sink))
        float pd = 0.f;
        if (c == 15) {
#pragma unroll
            for (int i = 0; i < 16; ++i) {
                int st8 = 16 * (i >> 2) + 4 * q + (i & 3);
                pd += v[i] * sf * __expf(sink[st8]);
            }
        }
        pd += __shfl_xor(pd, 16, 64);
        pd += __shfl_xor(pd, 32, 64);
        if (lane == 15) dotSh = pd;
    }
    __syncthreads();
    if (w == 0) {
        float t2 = sC[lane & 63];
#pragma unroll
        for (int m = 32; m >= 1; m >>= 1) t2 += __shfl_xor(t2, m, 64);
        if (lane == 0) {
            float gold = gW[0] + gW[1] + gW[2] + gW[3];
            float part = t2 - gold;
            if (half) part += logf(dotSh);
            partOut[bid] = part;
        }
    }
}

__global__ __launch_bounds__(256) void crf_finish(
    const float* __restrict__ part, float* __restrict__ out)
{
    const int bt = threadIdx.x;
    __shared__ float red[256];
    red[bt] = part[2 * bt] + part[2 * bt + 1];
    __syncthreads();
    for (int s2 = 128; s2 > 0; s2 >>= 1) {
        if (bt < s2) red[bt] += red[bt + s2];
        __syncthreads();
    }
    if (bt == 0) out[0] = red[0] * (1.0f / CRF_B);
}

extern "C" void kernel_launch(void* const* d_in, const int* in_sizes, int n_in,
                              void* d_out, int out_size, void* d_ws, size_t ws_size,
                              hipStream_t stream) {
    const float* scores = (const float*)d_in[0];
    const int*   states = (const int*)d_in[1];
    const float* trans  = (const float*)d_in[2];
    const float* source = (const float*)d_in[3];
    const float* sink   = (const float*)d_in[4];

    float* part = (float*)d_ws;   // 512 per-(batch,half) partials
    float* out = (float*)d_out;

    crf_scan<<<CRF_B * 2, 256, 0, stream>>>(scores, states, trans, source, sink, part);
    crf_finish<<<1, 256, 0, stream>>>(part, out);
}